// Round 1
// baseline (542.537 us; speedup 1.0000x reference)
//
#include <hip/hip_runtime.h>
#include <math.h>

typedef float v4 __attribute__((ext_vector_type(4)));

#define HD 1024      // hidden dim
#define NB 64        // batch
#define NCHUNK 16    // i-chunks in update kernel

// ws layout (float offsets)
#define WS_XT      0         // Xt4 [256][64] float4  = 65536 floats
#define WS_HT      65536     // Ht4 same
#define WS_IGT     131072    // igT [1024][64]
#define WS_FGT     196608    // fgT [1024][64]
#define WS_QT      262144    // qT  [1024][64]
#define WS_VT      327680    // vT  [1024][64]
#define WS_OGN     393216    // ogN [64][1024]
#define WS_KN      458752    // kN  [64][1024]
#define WS_PART    524288    // partial [16][64][1024] = 1048576 floats
// total = 1572864 floats = 6.29 MB

// ---------------- kernel 1: transpose input/h to k-major float4 panels ----------
__global__ __launch_bounds__(256) void k_transpose(const float* __restrict__ input,
                                                   const float* __restrict__ h,
                                                   float* __restrict__ ws) {
    int g = blockIdx.x * 256 + threadIdx.x;   // 0..32767
    int which = g >> 14;                      // 0=input, 1=h
    int idx = g & 16383;                      // 0..16383
    int kk = idx >> 6;                        // 0..255 (float4 index along k)
    int b  = idx & 63;
    const float* src = which ? h : input;
    v4 val = *(const v4*)(src + (size_t)b * HD + kk * 4);   // 16B per lane, gather across b-rows (tiny)
    v4* dst = (v4*)(ws + (which ? WS_HT : WS_XT));
    dst[kk * 64 + b] = val;                   // coalesced: lanes consecutive in b
}

// ---------------- kernel 2: gates + q/k/v GEMM ----------------
// One wave per output row r; lanes = batch. Weight row is wave-uniform -> scalar loads.
__global__ __launch_bounds__(256) void k_gemm(
    const float* __restrict__ Wih, const float* __restrict__ Whh, const float* __restrict__ bias,
    const float* __restrict__ Wq, const float* __restrict__ Wqb,
    const float* __restrict__ Wk, const float* __restrict__ Wkb,
    const float* __restrict__ Wv, const float* __restrict__ Wvb,
    float* __restrict__ ws) {
    const v4* Xt = (const v4*)(ws + WS_XT);
    const v4* Ht = (const v4*)(ws + WS_HT);
    int lane = threadIdx.x & 63;
    int wid  = __builtin_amdgcn_readfirstlane(threadIdx.x >> 6);
    int blk  = blockIdx.x;

    if (blk < 768) {
        // gates rows: r in [0,3072)
        int r = blk * 4 + wid;
        const v4* wr1 = (const v4*)(Wih + (size_t)r * HD);
        const v4* wr2 = (const v4*)(Whh + (size_t)r * HD);
        float acc = 0.f;
        for (int kk = 0; kk < 256; ++kk) {
            v4 w = wr1[kk];
            v4 x = Xt[kk * 64 + lane];
            acc += w.x * x.x + w.y * x.y + w.z * x.z + w.w * x.w;
        }
        for (int kk = 0; kk < 256; ++kk) {
            v4 w = wr2[kk];
            v4 x = Ht[kk * 64 + lane];
            acc += w.x * x.x + w.y * x.y + w.z * x.z + w.w * x.w;
        }
        acc += bias[r];
        if (r < 1024) {
            ws[WS_IGT + r * 64 + lane] = expf(acc);
        } else if (r < 2048) {
            ws[WS_FGT + (r - 1024) * 64 + lane] = expf(acc);
        } else {
            float o = 1.f / (1.f + expf(-acc));
            ws[WS_OGN + lane * HD + (r - 2048)] = o;   // natural layout (scatter, small)
        }
    } else {
        // q/k/v rows: r2 in [0,3072)
        int r2 = (blk - 768) * 4 + wid;
        int sel = r2 >> 10;
        int rr  = r2 & 1023;
        const float* W  = (sel == 0) ? Wq  : (sel == 1) ? Wk  : Wv;
        const float* Bv = (sel == 0) ? Wqb : (sel == 1) ? Wkb : Wvb;
        const v4* wr = (const v4*)(W + (size_t)rr * HD);
        float acc = 0.f;
        for (int kk = 0; kk < 256; ++kk) {
            v4 w = wr[kk];
            v4 x = Xt[kk * 64 + lane];
            acc += w.x * x.x + w.y * x.y + w.z * x.z + w.w * x.w;
        }
        acc += Bv[rr];
        if (sel == 0)      ws[WS_QT + rr * 64 + lane] = acc;
        else if (sel == 1) ws[WS_KN + lane * HD + rr] = acc;   // natural layout for phase 2
        else               ws[WS_VT + rr * 64 + lane] = acc;
    }
}

// ---------------- kernel 3: C update + fused readout partials ----------------
// grid = 64 b * 16 chunks; block 256 threads, thread owns 4 columns (float4).
__global__ __launch_bounds__(256) void k_update(const float* __restrict__ C,
                                                float* __restrict__ out,
                                                float* __restrict__ ws) {
    int b  = blockIdx.x >> 4;
    int c  = blockIdx.x & 15;
    int i0 = c << 6;
    int tid = threadIdx.x;

    __shared__ float fg_s[64], iv_s[64], q_s[64];
    if (tid < 64) {
        int i = i0 + tid;
        fg_s[tid] = ws[WS_FGT + i * 64 + b];
        iv_s[tid] = ws[WS_IGT + i * 64 + b] * ws[WS_VT + i * 64 + b];
        q_s[tid]  = ws[WS_QT + i * 64 + b];
    }
    __syncthreads();

    v4 k4 = *(const v4*)(ws + WS_KN + b * HD + tid * 4);
    const v4* Cb = (const v4*)(C + (size_t)b * HD * HD) + tid;            // + i*256 per row
    v4*       On = (v4*)(out + NB * HD + (size_t)b * HD * HD) + tid;
    v4 acc = {0.f, 0.f, 0.f, 0.f};

    for (int ii = 0; ii < 64; ++ii) {
        int i = i0 + ii;
        v4 c4 = __builtin_nontemporal_load(&Cb[(size_t)i * 256]);
        float fi = fg_s[ii], ivi = iv_s[ii], qi = q_s[ii];
        v4 cn;
        cn.x = fi * c4.x + ivi * k4.x;
        cn.y = fi * c4.y + ivi * k4.y;
        cn.z = fi * c4.z + ivi * k4.z;
        cn.w = fi * c4.w + ivi * k4.w;
        __builtin_nontemporal_store(cn, &On[(size_t)i * 256]);
        acc.x += qi * cn.x;
        acc.y += qi * cn.y;
        acc.z += qi * cn.z;
        acc.w += qi * cn.w;
    }
    *(v4*)(ws + WS_PART + (size_t)(c * 64 + b) * HD + tid * 4) = acc;
}

// ---------------- kernel 4: finalize h ----------------
__global__ __launch_bounds__(256) void k_final(float* __restrict__ out,
                                               const float* __restrict__ ws) {
    int b = blockIdx.x;
    int tid = threadIdx.x;
    const v4* part = (const v4*)(ws + WS_PART);
    v4 s = {0.f, 0.f, 0.f, 0.f};
    for (int c = 0; c < NCHUNK; ++c) {
        v4 p = part[(size_t)(c * 64 + b) * 256 + tid];
        s.x += p.x; s.y += p.y; s.z += p.z; s.w += p.w;
    }
    v4 o4 = *(const v4*)(ws + WS_OGN + b * HD + tid * 4);
    v4 r;
    r.x = o4.x * s.x; r.y = o4.y * s.y; r.z = o4.z * s.z; r.w = o4.w * s.w;
    *(v4*)(out + b * HD + tid * 4) = r;
}

extern "C" void kernel_launch(void* const* d_in, const int* in_sizes, int n_in,
                              void* d_out, int out_size, void* d_ws, size_t ws_size,
                              hipStream_t stream) {
    const float* input = (const float*)d_in[0];
    const float* h     = (const float*)d_in[1];
    const float* C     = (const float*)d_in[2];
    const float* Wih   = (const float*)d_in[3];
    const float* Whh   = (const float*)d_in[4];
    const float* bias  = (const float*)d_in[5];
    const float* Wq_w  = (const float*)d_in[6];
    const float* Wq_b  = (const float*)d_in[7];
    const float* Wk_w  = (const float*)d_in[8];
    const float* Wk_b  = (const float*)d_in[9];
    const float* Wv_w  = (const float*)d_in[10];
    const float* Wv_b  = (const float*)d_in[11];
    float* out = (float*)d_out;
    float* ws  = (float*)d_ws;

    k_transpose<<<128, 256, 0, stream>>>(input, h, ws);
    k_gemm<<<1536, 256, 0, stream>>>(Wih, Whh, bias, Wq_w, Wq_b, Wk_w, Wk_b, Wv_w, Wv_b, ws);
    k_update<<<1024, 256, 0, stream>>>(C, out, ws);
    k_final<<<64, 256, 0, stream>>>(out, ws);
}